// Round 1
// baseline (149.153 us; speedup 1.0000x reference)
//
#include <hip/hip_runtime.h>
#include <hip/hip_bf16.h>

typedef __hip_bfloat16 bf16;
typedef __attribute__((ext_vector_type(8))) short short8;
typedef __attribute__((ext_vector_type(4))) float floatx4;

#define DEVI __device__ __forceinline__

DEVI float b2f(bf16 v) { return __bfloat162float(v); }
DEVI bf16 f2b(float v) { return __float2bfloat16(v); }
DEVI unsigned short f2bu(float v) {
    bf16 h = __float2bfloat16(v);
    unsigned short u;
    __builtin_memcpy(&u, &h, 2);
    return u;
}
DEVI float sigmoidf_(float z) { return 1.0f / (1.0f + __expf(-z)); }

// Problem constants
// B=8, H=W=56, C=192, WS=4 -> 14x14 windows, 1568 rows (=98*16), ind=3072,
// hid=ncl=256.  ALL inputs/outputs are float32.
//
// MFMA fragment conventions (mfma_f32_16x16x32_bf16):
//   A[m][k]: lane = quad*16 + m15 -> m = m15, k = quad*8 + j  (16B contiguous)
//   B[k][n]: lane = quad*16 + n15 -> k = quad*8 + j, n = n15
//   D[m][n]: col n = lane&15, row m = quad*4 + reg
//
// Key algebraic identities used:
//   sigmoid(L) > 0.5  <=>  L > 0      (tm literals need only logit signs)
//   clause = AND over included literals of (lit > 0.5)   (min>tau <=> all>tau)
//   feat = sigmoid(clauses @ (vote_w@W2/16) + b2)        (logits not an output)

// ---------------------------------------------------------------------------
// K0 (merged pre): block-ranged fusion of 4 independent preprocessing stages.
// SLOW branches first so they start in dispatch round 0 (tail-shaving):
//   [0, 768)      : vw2 = vote_w @ W2 / 16 via MFMA -> vw2frag (bf16 B-frag)
//   [768, 1152)   : W1 f32 -> bf16 B-fragment repack -> w1frag
//   [1152, 1168)  : inc bitmask (inc = inc_w > 0) -> mask[word(16)][clause(256)]
//   [1168, 7440)  : LayerNorm + roll(-2,-2) + window partition -> win (bf16)
__global__ __launch_bounds__(256) void pre_kernel(const float* __restrict__ x,
                                                  const float* __restrict__ gamma,
                                                  const float* __restrict__ beta,
                                                  const float* __restrict__ vote_w,
                                                  const float* __restrict__ W2,
                                                  const float* __restrict__ W1,
                                                  const float* __restrict__ inc_w,
                                                  bf16* __restrict__ win,
                                                  unsigned short* __restrict__ vw2frag,
                                                  unsigned short* __restrict__ w1frag,
                                                  unsigned* __restrict__ mask) {
    int bx = blockIdx.x;
    int t = threadIdx.x;
    if (bx < 768) {
        // ---- vw2 MFMA: M=256(k_out), N=3072, K=192 ----
        int bid = bx;                  // 0..767
        int wave = t >> 6;
        int lane = t & 63;
        int quad = lane >> 4;
        int l15 = lane & 15;
        int mt = bid & 15;             // 16-wide k_out tile
        int nt = (bid >> 4) * 4 + wave; // 0..191: 16-wide n tile

        const float* ap = vote_w + (mt * 16 + l15) * 192 + quad * 8;
        const float* bp = W2 + (quad * 8) * 3072 + nt * 16 + l15;

        floatx4 acc = {0.f, 0.f, 0.f, 0.f};
#pragma unroll
        for (int kb = 0; kb < 6; kb++) {
            float4 a0 = *reinterpret_cast<const float4*>(ap + kb * 32);
            float4 a1 = *reinterpret_cast<const float4*>(ap + kb * 32 + 4);
            short8 a, b;
            a[0] = (short)f2bu(a0.x); a[1] = (short)f2bu(a0.y);
            a[2] = (short)f2bu(a0.z); a[3] = (short)f2bu(a0.w);
            a[4] = (short)f2bu(a1.x); a[5] = (short)f2bu(a1.y);
            a[6] = (short)f2bu(a1.z); a[7] = (short)f2bu(a1.w);
#pragma unroll
            for (int j = 0; j < 8; j++) {
                b[j] = (short)f2bu(bp[(kb * 32 + j) * 3072]);
            }
            acc = __builtin_amdgcn_mfma_f32_16x16x32_bf16(a, b, acc, 0, 0, 0);
        }
#pragma unroll
        for (int r = 0; r < 4; r++) {
            int k = mt * 16 + quad * 4 + r;  // gemm2 k index (0..255)
            int off = ((nt * 8 + (k >> 5)) * 64 + ((k >> 3) & 3) * 16 + l15) * 8 + (k & 7);
            vw2frag[off] = f2bu(acc[r] * 0.0625f);  // 1/sqrt(256)
        }
    } else if (bx < 1152) {
        // ---- W1 repack: one 1KB fragment per wave, coalesced 16B/lane stores ----
        int bid = bx - 768;            // 0..383
        int lane = t & 63;
        int fid = bid * 4 + (t >> 6);  // = nb*96 + kb
        int nb = fid / 96;
        int kb = fid - nb * 96;
        int n = nb * 16 + (lane & 15);
        int k = kb * 32 + (lane >> 4) * 8;
        short8 v;
#pragma unroll
        for (int j = 0; j < 8; j++) {
            v[j] = (short)f2bu(W1[(k + j) * 256 + n]);
        }
        *reinterpret_cast<short8*>(w1frag + ((size_t)fid * 64 + lane) * 8) = v;
    } else if (bx < 1168) {
        // ---- inc bitmask ----
        int wi = bx - 1152;            // 0..15
        unsigned bits = 0u;
        int base = t * 512 + wi * 32;
#pragma unroll
        for (int b = 0; b < 32; b++) {
            if (inc_w[base + b] > 0.0f) bits |= (1u << b);
        }
        mask[wi * 256 + t] = bits;
    } else {
        // ---- LayerNorm + shift + window partition (1 pixel per wave) ----
        int blk = (bx - 1168) * 4 + (t >> 6);  // b*3136 + h'*56 + w'  (rolled coords)
        int w_ = blk % 56;
        int t2 = blk / 56;
        int h_ = t2 % 56;
        int b = t2 / 56;
        int hs = h_ + 2; if (hs >= 56) hs -= 56;
        int ws = w_ + 2; if (ws >= 56) ws -= 56;
        const float* xp = x + (((b * 56 + hs) * 56 + ws) * 192);
        int l = t & 63;
        float v0 = xp[l];
        float v1 = xp[l + 64];
        float v2 = xp[l + 128];
        float s = v0 + v1 + v2;
        float sq = v0 * v0 + v1 * v1 + v2 * v2;
#pragma unroll
        for (int m = 1; m < 64; m <<= 1) {
            s += __shfl_xor(s, m, 64);
            sq += __shfl_xor(sq, m, 64);
        }
        float mean = s * (1.0f / 192.0f);
        float var = sq * (1.0f / 192.0f) - mean * mean;
        float inv = rsqrtf(var + 1e-5f);
        int row = b * 196 + (h_ >> 2) * 14 + (w_ >> 2);
        int fb = ((h_ & 3) * 4 + (w_ & 3)) * 192;
        bf16* wp = win + row * 3072 + fb;
        wp[l]       = f2b((v0 - mean) * inv * gamma[l]       + beta[l]);
        wp[l + 64]  = f2b((v1 - mean) * inv * gamma[l + 64]  + beta[l + 64]);
        wp[l + 128] = f2b((v2 - mean) * inv * gamma[l + 128] + beta[l + 128]);
    }
}

// ---------------------------------------------------------------------------
// K1 (fused gemm1 + tm): win @ W1 signs -> clauses, no global partials.
// M=1568, N=256, K=3072.  Grid 98 blocks x 512 threads (8 waves).
// Each block owns a 16-row m-tile; wave w computes the FULL 16x256 logit tile
// over K-slice [w*384, w*384+384) -- bit-identical to the old 8-way split-K
// (same slice boundaries, same accumulation order, same b1-first final sum).
// Slices staged in LDS (row stride 264 floats -> exactly 2-way bank alias on
// the 4-row x 16-col acc stores, which is free), then reduced + ballot-signed
// + clause-AND'd + summarized entirely in-block.
__global__ __launch_bounds__(512) void gemm1_tm(const bf16* __restrict__ win,
                                                const unsigned short* __restrict__ w1frag,
                                                const float* __restrict__ b1,
                                                const unsigned* __restrict__ mask,
                                                float* __restrict__ cl_out,
                                                bf16* __restrict__ clauses_bf,
                                                float* __restrict__ sum_out) {
    __shared__ float accbuf[8][16][264];   // 135,168 B (pad 8 -> 2-way max on store)
    __shared__ unsigned g_s[16][16];       // per-row sign words (hi 8 / lo 8)
    __shared__ float red[16][4];           // per-row popcount partials
    int t = threadIdx.x;
    int wave = t >> 6;            // 0..7 = K-slice id (== old blockIdx.z)
    int lane = t & 63;
    int quad = lane >> 4;
    int mlo = lane & 15;
    int m0 = blockIdx.x * 16;

    const bf16* ap = win + (m0 + mlo) * 3072 + wave * 384 + quad * 8;
    const unsigned short* bp = w1frag + lane * 8;
    int kb0 = wave * 12;

    floatx4 acc[16];
#pragma unroll
    for (int i = 0; i < 16; i++) acc[i] = (floatx4){0.f, 0.f, 0.f, 0.f};

#pragma unroll 1
    for (int kb = 0; kb < 12; kb++) {
        short8 a = *reinterpret_cast<const short8*>(ap + kb * 32);
#pragma unroll
        for (int i = 0; i < 16; i++) {
            short8 b = *reinterpret_cast<const short8*>(
                bp + ((size_t)(i * 96 + kb0 + kb)) * 512);
            acc[i] = __builtin_amdgcn_mfma_f32_16x16x32_bf16(a, b, acc[i], 0, 0, 0);
        }
    }

    // stage this wave's 16x256 partial tile
#pragma unroll
    for (int i = 0; i < 16; i++) {
#pragma unroll
        for (int r = 0; r < 4; r++) {
            accbuf[wave][quad * 4 + r][i * 16 + mlo] = acc[i][r];
        }
    }
    __syncthreads();

    // reduce 8 slices + sign ballots.  512 threads = 2 halves x 256 cols;
    // half h handles rows h*8..h*8+7, col c = (wave&3)*64 + lane = t&255.
    int c = t & 255;
    int half = t >> 8;
    int w4 = wave & 3;
    float bb = b1[c];
    float L[8];
#pragma unroll
    for (int rr = 0; rr < 8; rr++) {
        int r = half * 8 + rr;
        float s = bb;
#pragma unroll
        for (int w = 0; w < 8; w++) s += accbuf[w][r][c];
        L[rr] = s;
    }
#pragma unroll
    for (int rr = 0; rr < 8; rr++) {
        int r = half * 8 + rr;
        unsigned long long bhi = __ballot(L[rr] > 0.0f);  // lit c
        unsigned long long blo = __ballot(L[rr] < 0.0f);  // lit 256+c
        if (lane == 0) {
            g_s[r][w4 * 2]         = (unsigned)bhi;
            g_s[r][w4 * 2 + 1]     = (unsigned)(bhi >> 32);
            g_s[r][8 + w4 * 2]     = (unsigned)blo;
            g_s[r][8 + w4 * 2 + 1] = (unsigned)(blo >> 32);
        }
    }
    __syncthreads();

    // clause AND: thread = clause c, 8 rows; mask words reused across rows.
    unsigned mw[16];
#pragma unroll
    for (int w = 0; w < 16; w++) mw[w] = mask[w * 256 + c];
#pragma unroll
    for (int rr = 0; rr < 8; rr++) {
        int r = half * 8 + rr;
        unsigned ok = 1u;
#pragma unroll
        for (int w = 0; w < 16; w++) {
            unsigned viol = mw[w] & (~g_s[r][w]);
            ok &= (viol == 0u) ? 1u : 0u;
        }
        float hard = (float)ok;
        int idx = (m0 + r) * 256 + c;
        cl_out[idx] = hard;
        clauses_bf[idx] = f2b(hard);
        unsigned long long cb = __ballot(ok != 0u);
        if (lane == 0) red[r][w4] = (float)__popcll(cb);
    }
    __syncthreads();
    if (t < 16) {
        sum_out[m0 + t] = (red[t][0] + red[t][1] + red[t][2] + red[t][3]) * (1.0f / 256.0f);
    }
}

// ---------------------------------------------------------------------------
// K2: fused  feat = sigmoid(clauses @ vw2 + b2)  +  window-reverse + roll(+2,+2)
// + gated residual -> out.  M=1568, N=3072, K=256.  grid (49, 24), 4 waves
// 2m x 2n, wave tile 16m x 64n (4 acc tiles).  feat never materialized.
__global__ __launch_bounds__(256) void gemm2_out(const bf16* __restrict__ clauses_bf,
                                                 const unsigned short* __restrict__ vw2frag,
                                                 const float* __restrict__ b2v,
                                                 const float* __restrict__ x,
                                                 const float* __restrict__ gate,
                                                 float* __restrict__ out) {
    int t = threadIdx.x;
    int wave = t >> 6;
    int lane = t & 63;
    int quad = lane >> 4;
    int mlo = lane & 15;
    int wm = wave & 1;
    int wn = wave >> 1;
    int m0 = blockIdx.x * 32 + wm * 16;
    int nb0 = blockIdx.y * 8 + wn * 4;  // 16-wide n-tile base (0..191)

    const bf16* ap = clauses_bf + (m0 + mlo) * 256 + quad * 8;
    const unsigned short* bp = vw2frag + lane * 8;

    floatx4 acc[4];
#pragma unroll
    for (int i = 0; i < 4; i++) acc[i] = (floatx4){0.f, 0.f, 0.f, 0.f};

#pragma unroll
    for (int kb = 0; kb < 8; kb++) {
        short8 a = *reinterpret_cast<const short8*>(ap + kb * 32);
#pragma unroll
        for (int i = 0; i < 4; i++) {
            short8 b = *reinterpret_cast<const short8*>(
                bp + ((size_t)((nb0 + i) * 8 + kb)) * 512);
            acc[i] = __builtin_amdgcn_mfma_f32_16x16x32_bf16(a, b, acc[i], 0, 0, 0);
        }
    }

    float g = sigmoidf_(gate[0]);
    // per-r inverse window mapping: m_g -> (batch, window-h, window-w)
    int bq[4], wh[4], ww[4];
#pragma unroll
    for (int r = 0; r < 4; r++) {
        int m_g = m0 + quad * 4 + r;
        bq[r] = m_g / 196;
        int rem = m_g - bq[r] * 196;
        wh[r] = rem / 14;
        ww[r] = rem - wh[r] * 14;
    }
#pragma unroll
    for (int i = 0; i < 4; i++) {
        int n_g = (nb0 + i) * 16 + mlo;
        int cell = n_g / 192;           // 0..15 (position inside 4x4 window)
        int ch = n_g - cell * 192;      // channel
        int cellh = cell >> 2;
        int cellw = cell & 3;
        float bb = b2v[n_g];
#pragma unroll
        for (int r = 0; r < 4; r++) {
            int hh = wh[r] * 4 + cellh + 2; if (hh >= 56) hh -= 56;  // roll(+2)
            int wc = ww[r] * 4 + cellw + 2; if (wc >= 56) wc -= 56;
            int gid = ((bq[r] * 56 + hh) * 56 + wc) * 192 + ch;
            float mv = sigmoidf_(acc[i][r] + bb);
            out[gid] = x[gid] + g * mv + (1.0f - g) * sigmoidf_(mv);
        }
    }
}

// ---------------------------------------------------------------------------
extern "C" void kernel_launch(void* const* d_in, const int* in_sizes, int n_in,
                              void* d_out, int out_size, void* d_ws, size_t ws_size,
                              hipStream_t stream) {
    const float* x      = (const float*)d_in[0];
    const float* gamma  = (const float*)d_in[1];
    const float* beta   = (const float*)d_in[2];
    const float* W1     = (const float*)d_in[3];
    const float* b1     = (const float*)d_in[4];
    const float* inc_w  = (const float*)d_in[5];
    const float* vote_w = (const float*)d_in[6];
    const float* W2     = (const float*)d_in[7];
    const float* b2v    = (const float*)d_in[8];
    const float* gate   = (const float*)d_in[9];

    char* ws = (char*)d_ws;
    // workspace carve (bytes), total ~13.6 MB (part eliminated):
    bf16*           win        = (bf16*)(ws + 0);                  // 9,633,792
    unsigned short* w1frag     = (unsigned short*)(ws + 9633792);  // 1,572,864
    unsigned short* vw2frag    = (unsigned short*)(ws + 11206656); // 1,572,864
    bf16*           clauses_bf = (bf16*)(ws + 12779520);           //   802,816
    unsigned*       mask       = (unsigned*)(ws + 13582336);       //    16,384

    float* out     = (float*)d_out;
    float* cl_out  = out + 4816896;            // clauses: 1568*256
    float* sum_out = cl_out + 401408;          // summary: 1568

    pre_kernel<<<7440, 256, 0, stream>>>(x, gamma, beta, vote_w, W2, W1, inc_w,
                                         win, vw2frag, w1frag, mask);
    gemm1_tm<<<98, 512, 0, stream>>>(win, w1frag, b1, mask, cl_out, clauses_bf, sum_out);
    gemm2_out<<<dim3(49, 24), 256, 0, stream>>>(clauses_bf, vw2frag, b2v, x, gate, out);
}